// Round 7
// baseline (1359.255 us; speedup 1.0000x reference)
//
#include <hip/hip_runtime.h>
#include <hip/hip_bf16.h>
#include <cstdint>
#include <cstddef>

// ---------- types ----------
typedef __attribute__((ext_vector_type(4))) float f32x4;
typedef __attribute__((ext_vector_type(8))) short bf16x8;   // 8 bf16 in 4 VGPRs

#define E_  6
#define B_  8192
#define H_  512

// ---------- bf16 split helpers ----------
__device__ __forceinline__ unsigned short f32_to_bf16_rn(float f) {
    uint32_t u = __float_as_uint(f);
    uint32_t r = (u + 0x7fffu + ((u >> 16) & 1u)) >> 16;   // round-to-nearest-even
    return (unsigned short)r;
}
__device__ __forceinline__ float bf16_to_f32(unsigned short h) {
    return __uint_as_float(((uint32_t)h) << 16);
}

// =====================================================================
// convert_h: f32 activations (optionally concat of two tensors) ->
// fragment-major hi/lo bf16 layout (16x16x32 frags):
//   chunk c = ((bm*NK + kstep)*8 + mfrag)*64 + lane   (16 B per chunk-lane)
//   element: b = bm*128 + mfrag*16 + (lane&15),  k = kstep*32 + (lane>>4)*8 + j
// Fast path: interior chunks (8 k's in one source, in-bounds) use 4x float2
// (8B-aligned for both the 1830-row and 256/512-row cases).
// =====================================================================
__global__ void convert_h_kernel(const float* __restrict__ srcA, const float* __restrict__ srcB,
                                 int splitA, int K_in, int NK, int nchunks,
                                 short* __restrict__ dhi, short* __restrict__ dlo)
{
    int c = blockIdx.x * 256 + threadIdx.x;
    if (c >= nchunks) return;
    int lane  = c & 63;
    int mf    = (c >> 6) & 7;
    int rest  = c >> 9;
    int kstep = rest % NK;
    int bm    = rest / NK;
    int b  = bm * 128 + mf * 16 + (lane & 15);
    int k0 = kstep * 32 + (lane >> 4) * 8;

    float vv[8];
    if (k0 + 7 < splitA) {
        const float* p = srcA + (size_t)b * splitA + k0;
#pragma unroll
        for (int h = 0; h < 4; ++h) {
            float2 x = *reinterpret_cast<const float2*>(p + 2 * h);
            vv[2 * h] = x.x; vv[2 * h + 1] = x.y;
        }
    } else if (k0 >= splitA && k0 + 7 < K_in) {
        const float* p = srcB + (size_t)b * (K_in - splitA) + (k0 - splitA);
#pragma unroll
        for (int h = 0; h < 4; ++h) {
            float2 x = *reinterpret_cast<const float2*>(p + 2 * h);
            vv[2 * h] = x.x; vv[2 * h + 1] = x.y;
        }
    } else {
#pragma unroll
        for (int j = 0; j < 8; ++j) {
            int k = k0 + j;
            float v = 0.f;
            if (k < K_in) {
                v = (k < splitA) ? srcA[(size_t)b * splitA + k]
                                 : srcB[(size_t)b * (K_in - splitA) + (k - splitA)];
            }
            vv[j] = v;
        }
    }

    union { short s[8]; int4 v; } uh, ul;
#pragma unroll
    for (int j = 0; j < 8; ++j) {
        unsigned short h = f32_to_bf16_rn(vv[j]);
        float rem = vv[j] - bf16_to_f32(h);
        unsigned short l = f32_to_bf16_rn(rem);
        uh.s[j] = (short)h;
        ul.s[j] = (short)l;
    }
    *reinterpret_cast<int4*>(dhi + (size_t)c * 8) = uh.v;
    *reinterpret_cast<int4*>(dlo + (size_t)c * 8) = ul.v;
}

// =====================================================================
// convert_w: w [E, K_in, 512] f32 -> fragment-major hi/lo bf16 (16x16x32):
//   chunk c = (((e*8 + bn)*NK + kstep)*4 + nfrag)*64 + lane
//   element: o = bn*64 + nfrag*16 + (lane&15), k = kstep*32 + (lane>>4)*8 + j
// =====================================================================
__global__ void convert_w_kernel(const float* __restrict__ w, int K_in, int NK, int nchunks,
                                 short* __restrict__ dhi, short* __restrict__ dlo)
{
    int c = blockIdx.x * 256 + threadIdx.x;
    if (c >= nchunks) return;
    int lane  = c & 63;
    int nf    = (c >> 6) & 3;
    int rest  = c >> 8;
    int kstep = rest % NK;
    int eb    = rest / NK;
    int bn    = eb & 7;
    int e     = eb >> 3;
    int o  = bn * 64 + nf * 16 + (lane & 15);
    int k0 = kstep * 32 + (lane >> 4) * 8;

    union { short s[8]; int4 v; } uh, ul;
#pragma unroll
    for (int j = 0; j < 8; ++j) {
        int k = k0 + j;
        float v = 0.f;
        if (k < K_in) v = w[((size_t)e * K_in + k) * H_ + o];
        unsigned short h = f32_to_bf16_rn(v);
        float rem = v - bf16_to_f32(h);
        unsigned short l = f32_to_bf16_rn(rem);
        uh.s[j] = (short)h;
        ul.s[j] = (short)l;
    }
    *reinterpret_cast<int4*>(dhi + (size_t)c * 8) = uh.v;
    *reinterpret_cast<int4*>(dlo + (size_t)c * 8) = ul.v;
}

// =====================================================================
// blend_gemm v6 — 3 phases/k-step (2 experts, 48 MFMA per cluster):
//   out[b,o] = elu( sum_e coef[b,e]*(sum_k A[b,k] W_e[k,o] + bias[e,o]) )
// BM=128, BN=64, BK=32, 256 threads = 4 waves, wave tile 64x32 (4x2 frags).
// LDS 64 KB: A single buf (16KB) + 3 static B slots of 16KB (2 experts).
// Phase p of k-step s covers experts {2p, 2p+1}; B slot index == p.
// Issues (2 phases ahead): p0: B->slot2 (p2,s); p1: B->slot0 (p0,s+1)
//   then A(s+1); p2: B->slot1 (p1,s+1).
// Steady waits (audited, per-wave in-flight order):
//   p0: vmcnt(4)  [drains B[p0,s]+A(s); keeps B[p1,s]]
//   p1: vmcnt(4)  [drains B[p1,s]; keeps B[p2,s]]
//   p2: vmcnt(8)  [drains B[p2,s]; keeps B[p0,s+1]+A(s+1)]
// Tail s==NK-1: p1 skips issues -> p2 wait = vmcnt(0). Only non-counted wait.
// Slot safety: issue at phase P targets the slot read at P-1, whose
// ds_reads are drained by the lgkmcnt(0)-before-barrier at P.
// A safety: A consumed into regs at p0; re-issued at p1 (after barrier).
// =====================================================================
__global__ __launch_bounds__(256, 2)
void blend_gemm_kernel(const short* __restrict__ Ah, const short* __restrict__ Al,
                       const short* __restrict__ Bh, const short* __restrict__ Bl,
                       const float* __restrict__ coef, const float* __restrict__ bias,
                       float* __restrict__ out, int NK)
{
    // shorts: A @ 0 (8192), B slot q @ 8192 + q*8192 (q=0..2). Total 32768.
    __shared__ __align__(16) short lds[32768];

    const int tid  = threadIdx.x;
    const int lane = tid & 63;
    const int wave = tid >> 6;
    const int wm   = wave >> 1;   // 0..1
    const int wn   = wave & 1;    // 0..1
    const int blk  = blockIdx.x;
    const int bn   = blk & 7;     // XCD-pinned weight slice
    const int bm   = blk >> 3;    // 0..63

    const size_t abase     = (size_t)bm * NK * 4096;   // shorts per array
    const size_t bstride_e = (size_t)8 * NK * 2048;    // shorts per expert
    const size_t bbase0    = (size_t)bn * NK * 2048;

    auto issueA = [&](int s) {
        const size_t a_s = abase + (size_t)s * 4096;
        short* dst = &lds[0];
#pragma unroll
        for (int i = 0; i < 4; ++i) {
            const int ch = wave * 4 + i;
            const short* g = (ch < 8) ? (Ah + a_s + ch * 512)
                                      : (Al + a_s + (ch - 8) * 512);
            __builtin_amdgcn_global_load_lds(
                (const __attribute__((address_space(1))) short*)(g + lane * 8),
                (__attribute__((address_space(3))) short*)(dst + ch * 512),
                16, 0, 0);
        }
    };
    // stage experts {2p, 2p+1} of k-step s into B slot `slot`
    auto issueB = [&](int slot, int p, int s) {
        short* dst = &lds[8192 + slot * 8192];
        const size_t base = bbase0 + (size_t)s * 2048;
#pragma unroll
        for (int i = 0; i < 4; ++i) {
            const int ch   = wave * 4 + i;        // 0..15
            const int eSub = ch >> 3;             // 0..1
            const int t    = ch & 7;              // 0..3 hi, 4..7 lo
            const size_t off = (size_t)(2 * p + eSub) * bstride_e + base + (size_t)(t & 3) * 512;
            const short* g = ((t < 4) ? Bh : Bl) + off;
            __builtin_amdgcn_global_load_lds(
                (const __attribute__((address_space(1))) short*)(g + lane * 8),
                (__attribute__((address_space(3))) short*)(dst + ch * 512),
                16, 0, 0);
        }
    };

    const f32x4 zero = {0.f, 0.f, 0.f, 0.f};
    f32x4 acc[E_][4][2];
#pragma unroll
    for (int e = 0; e < E_; ++e)
#pragma unroll
        for (int mf = 0; mf < 4; ++mf)
#pragma unroll
            for (int nf = 0; nf < 2; ++nf) acc[e][mf][nf] = zero;

    bf16x8 ah[4], al4[4];   // A frags held across the 3 phases of a k-step

    // prologue: order matters for p0(0)'s vmcnt(4):
    //   B[p0(0)] (oldest), A(0), B[p1(0)] (youngest 4, stays in flight)
    __builtin_amdgcn_sched_barrier(0);
    issueB(0, 0, 0);
    issueA(0);
    issueB(1, 1, 0);
    __builtin_amdgcn_sched_barrier(0);

    for (int s = 0; s < NK; ++s) {
        const bool lastS = (s == NK - 1);
#pragma unroll
        for (int p = 0; p < 3; ++p) {
            // ---- phase-entry wait + single barrier ----
            if (p == 0) {
                asm volatile("s_waitcnt vmcnt(4) lgkmcnt(0)" ::: "memory");
            } else if (p == 1) {
                asm volatile("s_waitcnt vmcnt(4) lgkmcnt(0)" ::: "memory");
            } else {
                if (!lastS) asm volatile("s_waitcnt vmcnt(8) lgkmcnt(0)" ::: "memory");
                else        asm volatile("s_waitcnt vmcnt(0) lgkmcnt(0)" ::: "memory");
            }
            __builtin_amdgcn_s_barrier();
            __builtin_amdgcn_sched_barrier(0);

            // ---- issues (target slot read at previous phase) ----
            if (p == 0) {
                issueB(2, 2, s);
            } else if (p == 1) {
                if (!lastS) { issueB(0, 0, s + 1); issueA(s + 1); }
            } else {
                if (!lastS) issueB(1, 1, s + 1);
            }
            __builtin_amdgcn_sched_barrier(0);

            // ---- fragment reads ----
            if (p == 0) {
                const short* Ab = &lds[0];
#pragma unroll
                for (int mf = 0; mf < 4; ++mf) {
                    ah[mf]  = *reinterpret_cast<const bf16x8*>(&Ab[((wm * 4 + mf) * 64 + lane) * 8]);
                    al4[mf] = *reinterpret_cast<const bf16x8*>(&Ab[((8 + wm * 4 + mf) * 64 + lane) * 8]);
                }
            }
            const short* Bb = &lds[8192 + p * 8192];
            bf16x8 bh[2][2], bl[2][2];   // [eSub][nf]
#pragma unroll
            for (int eSub = 0; eSub < 2; ++eSub)
#pragma unroll
                for (int nf = 0; nf < 2; ++nf) {
                    bh[eSub][nf] = *reinterpret_cast<const bf16x8*>(&Bb[((eSub * 8 +     wn * 2 + nf) * 64 + lane) * 8]);
                    bl[eSub][nf] = *reinterpret_cast<const bf16x8*>(&Bb[((eSub * 8 + 4 + wn * 2 + nf) * 64 + lane) * 8]);
                }

            // ---- MFMA cluster: 48 x 16x16x32 (2 experts) ----
            __builtin_amdgcn_s_setprio(1);
#pragma unroll
            for (int eSub = 0; eSub < 2; ++eSub) {
                const int e = 2 * p + eSub;
#pragma unroll
                for (int mf = 0; mf < 4; ++mf)
#pragma unroll
                    for (int nf = 0; nf < 2; ++nf) {
                        acc[e][mf][nf] = __builtin_amdgcn_mfma_f32_16x16x32_bf16(ah[mf],  bh[eSub][nf], acc[e][mf][nf], 0, 0, 0);
                        acc[e][mf][nf] = __builtin_amdgcn_mfma_f32_16x16x32_bf16(ah[mf],  bl[eSub][nf], acc[e][mf][nf], 0, 0, 0);
                        acc[e][mf][nf] = __builtin_amdgcn_mfma_f32_16x16x32_bf16(al4[mf], bh[eSub][nf], acc[e][mf][nf], 0, 0, 0);
                    }
            }
            __builtin_amdgcn_s_setprio(0);
            __builtin_amdgcn_sched_barrier(0);
        }
    }

    // ---- epilogue: blend + bias + ELU + store ----
    float bb[E_][2];
#pragma unroll
    for (int nf = 0; nf < 2; ++nf) {
        const int col = bn * 64 + wn * 32 + nf * 16 + (lane & 15);
#pragma unroll
        for (int e = 0; e < E_; ++e) bb[e][nf] = bias[e * H_ + col];
    }

#pragma unroll
    for (int mf = 0; mf < 4; ++mf) {
        const int r0 = bm * 128 + wm * 64 + mf * 16 + (lane >> 4) * 4;
#pragma unroll
        for (int q = 0; q < 4; ++q) {
            const int r = r0 + q;
            const float2* c2 = reinterpret_cast<const float2*>(coef + (size_t)r * E_);
            float2 ca = c2[0], cb = c2[1], cc = c2[2];
            float cf[E_] = {ca.x, ca.y, cb.x, cb.y, cc.x, cc.y};
#pragma unroll
            for (int nf = 0; nf < 2; ++nf) {
                const int col = bn * 64 + wn * 32 + nf * 16 + (lane & 15);
                float v = 0.f;
#pragma unroll
                for (int e = 0; e < E_; ++e)
                    v += cf[e] * (acc[e][mf][nf][q] + bb[e][nf]);
                v = v > 0.f ? v : expm1f(v);
                out[(size_t)r * H_ + col] = v;
            }
        }
    }
}

// =====================================================================
// host launcher
// =====================================================================
extern "C" void kernel_launch(void* const* d_in, const int* in_sizes, int n_in,
                              void* d_out, int out_size, void* d_ws, size_t ws_size,
                              hipStream_t stream)
{
    if (n_in < 9) return;
    const float* frame = (const float*)d_in[0];   // [8192,1830]
    const float* Iin   = (const float*)d_in[1];   // [8192,256]
    const float* coef  = (const float*)d_in[2];   // [8192,6]
    const float* w1    = (const float*)d_in[3];   // [6,2086,512]
    const float* b1    = (const float*)d_in[4];   // [6,512]
    const float* w2    = (const float*)d_in[5];   // [6,512,512]
    const float* b2    = (const float*)d_in[6];
    const float* w3    = (const float*)d_in[7];
    const float* b3    = (const float*)d_in[8];
    float* out = (float*)d_out;
    char* ws = (char*)d_ws;

    const int NK1 = 66;   // ceil(2086/32) -> K padded to 2112
    const int NK2 = 16;   // 512/32

    const size_t A0sz = (size_t)8192 * 2112 * 2;     // bytes per hi/lo array
    const size_t W1sz = (size_t)6 * 2112 * 512 * 2;
    const size_t W2sz = (size_t)6 * 512 * 512 * 2;
    const size_t H1f  = (size_t)8192 * 512 * 4;
    const size_t H1b  = (size_t)8192 * 512 * 2;

    const size_t need = 2 * A0sz + 2 * W1sz + 4 * W2sz + H1f + 2 * H1b;
    if (ws_size < need) return;

    short* A0h = (short*)(ws);
    short* A0l = (short*)(ws + A0sz);
    short* w1h = (short*)(ws + 2 * A0sz);
    short* w1l = (short*)(ws + 2 * A0sz + W1sz);
    short* w2h = (short*)(ws + 2 * A0sz + 2 * W1sz);
    short* w2l = (short*)(ws + 2 * A0sz + 2 * W1sz + W2sz);
    short* w3h = (short*)(ws + 2 * A0sz + 2 * W1sz + 2 * W2sz);
    short* w3l = (short*)(ws + 2 * A0sz + 2 * W1sz + 3 * W2sz);
    float* h1  = (float*)(ws + 2 * A0sz + 2 * W1sz + 4 * W2sz);
    short* h1h = (short*)((char*)h1 + H1f);
    short* h1l = (short*)((char*)h1 + H1f + H1b);
    // A0 region dead after GEMM1 -> reuse for layer-2 outputs
    float* h2  = (float*)(ws);
    short* h2h = (short*)(ws + H1f);
    short* h2l = (short*)(ws + H1f + H1b);

    // prep: fragment-major hi/lo conversions
    {
        int nch = (8192 / 128) * NK1 * 8 * 64;
        convert_h_kernel<<<nch / 256, 256, 0, stream>>>(frame, Iin, 1830, 2086, NK1, nch, A0h, A0l);
    }
    {
        int nch = 6 * 8 * NK1 * 4 * 64;
        convert_w_kernel<<<nch / 256, 256, 0, stream>>>(w1, 2086, NK1, nch, w1h, w1l);
    }
    {
        int nch = 6 * 8 * NK2 * 4 * 64;
        convert_w_kernel<<<nch / 256, 256, 0, stream>>>(w2, 512, NK2, nch, w2h, w2l);
        convert_w_kernel<<<nch / 256, 256, 0, stream>>>(w3, 512, NK2, nch, w3h, w3l);
    }

    const int grid = 512;   // 64 bm x 8 bn, bn = blk & 7 (XCD-pinned)
    // layer 1
    blend_gemm_kernel<<<grid, 256, 0, stream>>>(A0h, A0l, w1h, w1l, coef, b1, h1, NK1);
    {
        int nch = (8192 / 128) * NK2 * 8 * 64;
        convert_h_kernel<<<nch / 256, 256, 0, stream>>>(h1, nullptr, 512, 512, NK2, nch, h1h, h1l);
    }
    // layer 2
    blend_gemm_kernel<<<grid, 256, 0, stream>>>(h1h, h1l, w2h, w2l, coef, b2, h2, NK2);
    {
        int nch = (8192 / 128) * NK2 * 8 * 64;
        convert_h_kernel<<<nch / 256, 256, 0, stream>>>(h2, nullptr, 512, 512, NK2, nch, h2h, h2l);
    }
    // layer 3 -> final output
    blend_gemm_kernel<<<grid, 256, 0, stream>>>(h2h, h2l, w3h, w3l, coef, b3, out, NK2);
}

// Round 8
// 542.497 us; speedup vs baseline: 2.5056x; 2.5056x over previous
//
#include <hip/hip_runtime.h>
#include <hip/hip_bf16.h>
#include <cstdint>
#include <cstddef>

// ---------- types ----------
typedef __attribute__((ext_vector_type(4))) float f32x4;
typedef __attribute__((ext_vector_type(8))) short bf16x8;   // 8 bf16 in 4 VGPRs

#define E_  6
#define B_  8192
#define H_  512

// ---------- bf16 split helpers ----------
__device__ __forceinline__ unsigned short f32_to_bf16_rn(float f) {
    uint32_t u = __float_as_uint(f);
    uint32_t r = (u + 0x7fffu + ((u >> 16) & 1u)) >> 16;   // round-to-nearest-even
    return (unsigned short)r;
}
__device__ __forceinline__ float bf16_to_f32(unsigned short h) {
    return __uint_as_float(((uint32_t)h) << 16);
}

// =====================================================================
// convert_h_t: LDS-transpose convert. One block per (bm, kstep) tile
// (128 rows x 32 k). Load phase: 2 threads/row, float2 along k ->
// 128B contiguous per row (coalesced). Store f32 to tile[128][33]
// (pad => <=2-way bank aliasing = free). Write phase: fragment-major
// hi/lo chunks, 16B/lane fully coalesced:
//   chunk c = ((bm*NK + kstep)*8 + mfrag)*64 + lane
//   element: b = bm*128 + mfrag*16 + (lane&15), k = kstep*32 + (lane>>4)*8 + j
// =====================================================================
__global__ __launch_bounds__(256)
void convert_h_t_kernel(const float* __restrict__ srcA, const float* __restrict__ srcB,
                        int splitA, int K_in, int NK,
                        short* __restrict__ dhi, short* __restrict__ dlo)
{
    __shared__ float tile[128][33];
    const int t     = threadIdx.x;
    const int kstep = blockIdx.x;
    const int bm    = blockIdx.y;

    // ---- load: 2 threads per row, 16 k each ----
    {
        const int r2   = t >> 1;
        const int half = t & 1;
        const int row  = bm * 128 + r2;
        const int kb   = kstep * 32 + half * 16;
        float* dstrow  = &tile[r2][half * 16];
        if (kb + 15 < splitA) {
            const float* p = srcA + (size_t)row * splitA + kb;
#pragma unroll
            for (int j = 0; j < 8; ++j) {
                float2 x = *reinterpret_cast<const float2*>(p + 2 * j);
                dstrow[2 * j] = x.x; dstrow[2 * j + 1] = x.y;
            }
        } else if (kb >= splitA && kb + 15 < K_in) {
            const float* p = srcB + (size_t)row * (K_in - splitA) + (kb - splitA);
#pragma unroll
            for (int j = 0; j < 8; ++j) {
                float2 x = *reinterpret_cast<const float2*>(p + 2 * j);
                dstrow[2 * j] = x.x; dstrow[2 * j + 1] = x.y;
            }
        } else {
#pragma unroll
            for (int j = 0; j < 16; ++j) {
                const int k = kb + j;
                float v = 0.f;
                if (k < K_in) v = (k < splitA) ? srcA[(size_t)row * splitA + k]
                                               : srcB[(size_t)row * (K_in - splitA) + (k - splitA)];
                dstrow[j] = v;
            }
        }
    }
    __syncthreads();

    // ---- write: 2 lane-chunks per thread, coalesced 16B/lane ----
#pragma unroll
    for (int hc = 0; hc < 2; ++hc) {
        const int lc = t + hc * 256;      // 0..511
        const int mf = lc >> 6;
        const int l  = lc & 63;
        const int rl = mf * 16 + (l & 15);
        const int kl = (l >> 4) * 8;
        union { short s[8]; int4 v; } uh, ul;
#pragma unroll
        for (int j = 0; j < 8; ++j) {
            const float v = tile[rl][kl + j];
            const unsigned short hh = f32_to_bf16_rn(v);
            const float rem = v - bf16_to_f32(hh);
            uh.s[j] = (short)hh;
            ul.s[j] = (short)f32_to_bf16_rn(rem);
        }
        const size_t c = (((size_t)bm * NK + kstep) * 8 + mf) * 64 + l;
        *reinterpret_cast<int4*>(dhi + c * 8) = uh.v;
        *reinterpret_cast<int4*>(dlo + c * 8) = ul.v;
    }
}

// =====================================================================
// convert_w: w [E, K_in, 512] f32 -> fragment-major hi/lo bf16 (16x16x32):
//   chunk c = (((e*8 + bn)*NK + kstep)*4 + nfrag)*64 + lane
//   element: o = bn*64 + nfrag*16 + (lane&15), k = kstep*32 + (lane>>4)*8 + j
// =====================================================================
__global__ void convert_w_kernel(const float* __restrict__ w, int K_in, int NK, int nchunks,
                                 short* __restrict__ dhi, short* __restrict__ dlo)
{
    int c = blockIdx.x * 256 + threadIdx.x;
    if (c >= nchunks) return;
    int lane  = c & 63;
    int nf    = (c >> 6) & 3;
    int rest  = c >> 8;
    int kstep = rest % NK;
    int eb    = rest / NK;
    int bn    = eb & 7;
    int e     = eb >> 3;
    int o  = bn * 64 + nf * 16 + (lane & 15);
    int k0 = kstep * 32 + (lane >> 4) * 8;

    union { short s[8]; int4 v; } uh, ul;
#pragma unroll
    for (int j = 0; j < 8; ++j) {
        int k = k0 + j;
        float v = 0.f;
        if (k < K_in) v = w[((size_t)e * K_in + k) * H_ + o];
        unsigned short h = f32_to_bf16_rn(v);
        float rem = v - bf16_to_f32(h);
        unsigned short l = f32_to_bf16_rn(rem);
        uh.s[j] = (short)h;
        ul.s[j] = (short)l;
    }
    *reinterpret_cast<int4*>(dhi + (size_t)c * 8) = uh.v;
    *reinterpret_cast<int4*>(dlo + (size_t)c * 8) = ul.v;
}

// =====================================================================
// blend_gemm v5 (reverted verbatim — proven 261us/55% MfmaUtil):
// 16x16x32 MFMA, 3-deep B ring, ONE barrier per phase, counted vmcnt.
//   out[b,o] = elu( sum_e coef[b,e]*(sum_k A[b,k] W_e[k,o] + bias[e,o]) )
// BM=128, BN=64, BK=32, 256 threads = 4 waves, wave tile 64x32 (4x2 frags).
// Phase p=6s+e: { waitcnt vmcnt(N) lgkmcnt(0); s_barrier;
//                 issue B ring (+A(s+1) at e==3); ds_read; 24 MFMA }.
// vmcnt audit: e=0..3: N=2; e=4,5: N=6. Tail s==NK-1: e=4: N=2; e=5: N=0.
// NOTE (v6 post-mortem): do NOT widen phases to 2 experts — the extra
// 32 live B-frag VGPRs spill the 192-reg accumulator (WRITE_SIZE 1.9GB).
// =====================================================================
__global__ __launch_bounds__(256, 2)
void blend_gemm_kernel(const short* __restrict__ Ah, const short* __restrict__ Al,
                       const short* __restrict__ Bh, const short* __restrict__ Bl,
                       const float* __restrict__ coef, const float* __restrict__ bias,
                       float* __restrict__ out, int NK)
{
    // LDS 56 KB (shorts): A0@0, A1@8192 (16 chunks x 512 each),
    // B0@16384, B1@20480, B2@24576 (8 chunks x 512 each).
    __shared__ __align__(16) short lds[28672];

    const int tid  = threadIdx.x;
    const int lane = tid & 63;
    const int wave = tid >> 6;
    const int wm   = wave >> 1;   // 0..1
    const int wn   = wave & 1;    // 0..1
    const int blk  = blockIdx.x;
    const int bn   = blk & 7;     // XCD-pinned weight slice
    const int bm   = blk >> 3;    // 0..63

    const size_t abase     = (size_t)bm * NK * 4096;   // shorts per array
    const size_t bstride_e = (size_t)8 * NK * 2048;    // shorts per expert
    const size_t bbase0    = (size_t)bn * NK * 2048;

    auto issueA = [&](int s) {
        const size_t a_s = abase + (size_t)s * 4096;
        short* dst = &lds[(s & 1) * 8192];
#pragma unroll
        for (int i = 0; i < 4; ++i) {
            const int ch = wave * 4 + i;
            const short* g = (ch < 8) ? (Ah + a_s + ch * 512)
                                      : (Al + a_s + (ch - 8) * 512);
            __builtin_amdgcn_global_load_lds(
                (const __attribute__((address_space(1))) short*)(g + lane * 8),
                (__attribute__((address_space(3))) short*)(dst + ch * 512),
                16, 0, 0);
        }
    };
    // ebuf: LDS ring slot (0..2); eexp: expert id; s: k-step
    auto issueB = [&](int ebuf, int eexp, int s) {
        const size_t off = (size_t)eexp * bstride_e + bbase0 + (size_t)s * 2048;
        short* dst = &lds[16384 + ebuf * 4096];
#pragma unroll
        for (int i = 0; i < 2; ++i) {
            const int ch = wave * 2 + i;
            const short* g = (ch < 4) ? (Bh + off + ch * 512)
                                      : (Bl + off + (ch - 4) * 512);
            __builtin_amdgcn_global_load_lds(
                (const __attribute__((address_space(1))) short*)(g + lane * 8),
                (__attribute__((address_space(3))) short*)(dst + ch * 512),
                16, 0, 0);
        }
    };

    const f32x4 zero = {0.f, 0.f, 0.f, 0.f};
    f32x4 acc[E_][4][2];
#pragma unroll
    for (int e = 0; e < E_; ++e)
#pragma unroll
        for (int mf = 0; mf < 4; ++mf)
#pragma unroll
            for (int nf = 0; nf < 2; ++nf) acc[e][mf][nf] = zero;

    bf16x8 ah[4], al4[4];   // A frags held across the 6 phases of a k-step

    // prologue: A(0), B ring slots 0,1 (experts 0,1)
    __builtin_amdgcn_sched_barrier(0);
    issueA(0);
    issueB(0, 0, 0);
    issueB(1, 1, 0);
    __builtin_amdgcn_sched_barrier(0);

    for (int s = 0; s < NK; ++s) {
        const bool lastS = (s == NK - 1);
#pragma unroll
        for (int e = 0; e < 6; ++e) {
            // ---- phase-entry wait + single barrier ----
            if (e < 4) {
                asm volatile("s_waitcnt vmcnt(2) lgkmcnt(0)" ::: "memory");
            } else if (e == 4) {
                if (!lastS) asm volatile("s_waitcnt vmcnt(6) lgkmcnt(0)" ::: "memory");
                else        asm volatile("s_waitcnt vmcnt(2) lgkmcnt(0)" ::: "memory");
            } else {
                if (!lastS) asm volatile("s_waitcnt vmcnt(6) lgkmcnt(0)" ::: "memory");
                else        asm volatile("s_waitcnt vmcnt(0) lgkmcnt(0)" ::: "memory");
            }
            __builtin_amdgcn_s_barrier();
            __builtin_amdgcn_sched_barrier(0);

            // ---- issues (ring slot (e+2)%3 == slot read at phase e-1) ----
            if (e < 4) {
                issueB((e + 2) % 3, e + 2, s);
            } else if (!lastS) {
                issueB((e + 2) % 3, e - 4, s + 1);
            }
            if (e == 3 && !lastS) issueA(s + 1);
            __builtin_amdgcn_sched_barrier(0);

            // ---- fragment reads ----
            if (e == 0) {
                const short* Ab = &lds[(s & 1) * 8192];
#pragma unroll
                for (int mf = 0; mf < 4; ++mf) {
                    ah[mf]  = *reinterpret_cast<const bf16x8*>(&Ab[((wm * 4 + mf) * 64 + lane) * 8]);
                    al4[mf] = *reinterpret_cast<const bf16x8*>(&Ab[((8 + wm * 4 + mf) * 64 + lane) * 8]);
                }
            }
            const short* Bb = &lds[16384 + (e % 3) * 4096];
            bf16x8 bh[2], bl[2];
#pragma unroll
            for (int nf = 0; nf < 2; ++nf) {
                bh[nf] = *reinterpret_cast<const bf16x8*>(&Bb[((wn * 2 + nf) * 64 + lane) * 8]);
                bl[nf] = *reinterpret_cast<const bf16x8*>(&Bb[((4 + wn * 2 + nf) * 64 + lane) * 8]);
            }

            // ---- MFMA cluster: 24 x 16x16x32 ----
            __builtin_amdgcn_s_setprio(1);
#pragma unroll
            for (int mf = 0; mf < 4; ++mf)
#pragma unroll
                for (int nf = 0; nf < 2; ++nf) {
                    acc[e][mf][nf] = __builtin_amdgcn_mfma_f32_16x16x32_bf16(ah[mf],  bh[nf], acc[e][mf][nf], 0, 0, 0);
                    acc[e][mf][nf] = __builtin_amdgcn_mfma_f32_16x16x32_bf16(ah[mf],  bl[nf], acc[e][mf][nf], 0, 0, 0);
                    acc[e][mf][nf] = __builtin_amdgcn_mfma_f32_16x16x32_bf16(al4[mf], bh[nf], acc[e][mf][nf], 0, 0, 0);
                }
            __builtin_amdgcn_s_setprio(0);
            __builtin_amdgcn_sched_barrier(0);
        }
    }

    // ---- epilogue: blend + bias + ELU + store ----
    float bb[E_][2];
#pragma unroll
    for (int nf = 0; nf < 2; ++nf) {
        const int col = bn * 64 + wn * 32 + nf * 16 + (lane & 15);
#pragma unroll
        for (int e = 0; e < E_; ++e) bb[e][nf] = bias[e * H_ + col];
    }

#pragma unroll
    for (int mf = 0; mf < 4; ++mf) {
        const int r0 = bm * 128 + wm * 64 + mf * 16 + (lane >> 4) * 4;
#pragma unroll
        for (int q = 0; q < 4; ++q) {
            const int r = r0 + q;
            const float2* c2 = reinterpret_cast<const float2*>(coef + (size_t)r * E_);
            float2 ca = c2[0], cb = c2[1], cc = c2[2];
            float cf[E_] = {ca.x, ca.y, cb.x, cb.y, cc.x, cc.y};
#pragma unroll
            for (int nf = 0; nf < 2; ++nf) {
                const int col = bn * 64 + wn * 32 + nf * 16 + (lane & 15);
                float v = 0.f;
#pragma unroll
                for (int e = 0; e < E_; ++e)
                    v += cf[e] * (acc[e][mf][nf][q] + bb[e][nf]);
                v = v > 0.f ? v : expm1f(v);
                out[(size_t)r * H_ + col] = v;
            }
        }
    }
}

// =====================================================================
// host launcher
// =====================================================================
extern "C" void kernel_launch(void* const* d_in, const int* in_sizes, int n_in,
                              void* d_out, int out_size, void* d_ws, size_t ws_size,
                              hipStream_t stream)
{
    if (n_in < 9) return;
    const float* frame = (const float*)d_in[0];   // [8192,1830]
    const float* Iin   = (const float*)d_in[1];   // [8192,256]
    const float* coef  = (const float*)d_in[2];   // [8192,6]
    const float* w1    = (const float*)d_in[3];   // [6,2086,512]
    const float* b1    = (const float*)d_in[4];   // [6,512]
    const float* w2    = (const float*)d_in[5];   // [6,512,512]
    const float* b2    = (const float*)d_in[6];
    const float* w3    = (const float*)d_in[7];
    const float* b3    = (const float*)d_in[8];
    float* out = (float*)d_out;
    char* ws = (char*)d_ws;

    const int NK1 = 66;   // ceil(2086/32) -> K padded to 2112
    const int NK2 = 16;   // 512/32

    const size_t A0sz = (size_t)8192 * 2112 * 2;     // bytes per hi/lo array
    const size_t W1sz = (size_t)6 * 2112 * 512 * 2;
    const size_t W2sz = (size_t)6 * 512 * 512 * 2;
    const size_t H1f  = (size_t)8192 * 512 * 4;
    const size_t H1b  = (size_t)8192 * 512 * 2;

    const size_t need = 2 * A0sz + 2 * W1sz + 4 * W2sz + H1f + 2 * H1b;
    if (ws_size < need) return;

    short* A0h = (short*)(ws);
    short* A0l = (short*)(ws + A0sz);
    short* w1h = (short*)(ws + 2 * A0sz);
    short* w1l = (short*)(ws + 2 * A0sz + W1sz);
    short* w2h = (short*)(ws + 2 * A0sz + 2 * W1sz);
    short* w2l = (short*)(ws + 2 * A0sz + 2 * W1sz + W2sz);
    short* w3h = (short*)(ws + 2 * A0sz + 2 * W1sz + 2 * W2sz);
    short* w3l = (short*)(ws + 2 * A0sz + 2 * W1sz + 3 * W2sz);
    float* h1  = (float*)(ws + 2 * A0sz + 2 * W1sz + 4 * W2sz);
    short* h1h = (short*)((char*)h1 + H1f);
    short* h1l = (short*)((char*)h1 + H1f + H1b);
    // A0 region dead after GEMM1 -> reuse for layer-2 outputs
    float* h2  = (float*)(ws);
    short* h2h = (short*)(ws + H1f);
    short* h2l = (short*)(ws + H1f + H1b);

    // prep: fragment-major hi/lo conversions (LDS-transpose for activations)
    {
        dim3 g(NK1, 64);
        convert_h_t_kernel<<<g, 256, 0, stream>>>(frame, Iin, 1830, 2086, NK1, A0h, A0l);
    }
    {
        int nch = 6 * 8 * NK1 * 4 * 64;
        convert_w_kernel<<<nch / 256, 256, 0, stream>>>(w1, 2086, NK1, nch, w1h, w1l);
    }
    {
        int nch = 6 * 8 * NK2 * 4 * 64;
        convert_w_kernel<<<nch / 256, 256, 0, stream>>>(w2, 512, NK2, nch, w2h, w2l);
        convert_w_kernel<<<nch / 256, 256, 0, stream>>>(w3, 512, NK2, nch, w3h, w3l);
    }

    const int grid = 512;   // 64 bm x 8 bn, bn = blk & 7 (XCD-pinned)
    // layer 1
    blend_gemm_kernel<<<grid, 256, 0, stream>>>(A0h, A0l, w1h, w1l, coef, b1, h1, NK1);
    {
        dim3 g(NK2, 64);
        convert_h_t_kernel<<<g, 256, 0, stream>>>(h1, nullptr, 512, 512, NK2, h1h, h1l);
    }
    // layer 2
    blend_gemm_kernel<<<grid, 256, 0, stream>>>(h1h, h1l, w2h, w2l, coef, b2, h2, NK2);
    {
        dim3 g(NK2, 64);
        convert_h_t_kernel<<<g, 256, 0, stream>>>(h2, nullptr, 512, 512, NK2, h2h, h2l);
    }
    // layer 3 -> final output
    blend_gemm_kernel<<<grid, 256, 0, stream>>>(h2h, h2l, w3h, w3l, coef, b3, out, NK2);
}